// Round 1
// baseline (546.335 us; speedup 1.0000x reference)
//
#include <hip/hip_runtime.h>
#include <stdint.h>

#define NDIM 512
#define CDIM 128
#define MDIM (NDIM*NDIM)   // 262144

typedef unsigned short u16;
typedef __bf16 bf16v8 __attribute__((ext_vector_type(8)));
typedef float f32x4 __attribute__((ext_vector_type(4)));
typedef short s16x4 __attribute__((ext_vector_type(4)));

__device__ __forceinline__ u16 f2bf(float f){
  union { float f; uint32_t u; } v; v.f = f;
  uint32_t u = v.u;
  u += 0x7fffu + ((u >> 16) & 1u);   // round-to-nearest-even
  return (u16)(u >> 16);
}
__device__ __forceinline__ float sigm(float x){ return 1.0f/(1.0f + __expf(-x)); }
__device__ __forceinline__ f32x4 mfma_bf16(bf16v8 a, bf16v8 b, f32x4 c){
  return __builtin_amdgcn_mfma_f32_16x16x32_bf16(a, b, c, 0, 0, 0);
}

// ---------------------------------------------------------------------------
// K0: pack weights transposed to bf16. wt[d][k], d in [0,768):
//   d<256: w_proj[:,d] ; d<512: w_gate[:,d-256] ; d<640: w_gate_out[:,d-512]
//   d>=640: w_out[:,d-640]  (Wt2 region for K3)
// ---------------------------------------------------------------------------
__global__ void k0_prep(const float* __restrict__ wp, const float* __restrict__ wg,
                        const float* __restrict__ wgo, const float* __restrict__ wo,
                        u16* __restrict__ wt){
  const int d = blockIdx.x, k = threadIdx.x;
  float v;
  if (d < 256)      v = wp[k*256 + d];
  else if (d < 512) v = wg[k*256 + (d-256)];
  else if (d < 640) v = wgo[k*128 + (d-512)];
  else              v = wo[k*128 + (d-640)];
  wt[d*CDIM + k] = f2bf(v);
}

// ---------------------------------------------------------------------------
// K1: per 64 rows: LN(fp32) -> x(bf16,LDS) -> MFMA x@[w_proj|w_gate|w_gate_out]
//     pg = p*sigmoid(g)*mask -> LDS transpose -> AB[d][m] (d in [0,256), k-contig)
//     gate = sigmoid(go + b_gate_out) -> d_out (fp32, overwritten by K3)
// ---------------------------------------------------------------------------
__global__ __launch_bounds__(256) void k1_ln_proj(
    const float* __restrict__ act, const float* __restrict__ mask,
    const float* __restrict__ lns, const float* __restrict__ lno,
    const float* __restrict__ bgo, const u16* __restrict__ wt,
    u16* __restrict__ AB, float* __restrict__ gate)
{
  __shared__ __align__(16) u16 xs[64][136];    // pitch 272B: 2-way bank alias (free)
  __shared__ __align__(16) u16 pgs[256][72];   // [d][m], pitch 144B
  __shared__ float msk[64];
  const int t = threadIdx.x;
  const int m0 = blockIdx.x * 64;

  { // Phase 1: layernorm, 4 threads per row
    const int r = t >> 2, q = t & 3;
    const float4* rp = (const float4*)(act + (size_t)(m0 + r)*CDIM + q*32);
    float4 v[8];
    #pragma unroll
    for (int i = 0; i < 8; ++i) v[i] = rp[i];
    float s = 0.f, s2 = 0.f;
    #pragma unroll
    for (int i = 0; i < 8; ++i){
      s  += v[i].x + v[i].y + v[i].z + v[i].w;
      s2 += v[i].x*v[i].x + v[i].y*v[i].y + v[i].z*v[i].z + v[i].w*v[i].w;
    }
    s += __shfl_xor(s, 1);  s2 += __shfl_xor(s2, 1);
    s += __shfl_xor(s, 2);  s2 += __shfl_xor(s2, 2);
    const float mean = s * (1.f/128.f);
    const float rstd = rsqrtf(s2 * (1.f/128.f) - mean*mean + 1e-5f);
    const float4* lsp = (const float4*)(lns + q*32);
    const float4* lop = (const float4*)(lno + q*32);
    #pragma unroll
    for (int i = 0; i < 8; ++i){
      const float4 sc = lsp[i], of = lop[i];
      s16x4 pk;
      pk.x = (short)f2bf((v[i].x - mean)*rstd*sc.x + of.x);
      pk.y = (short)f2bf((v[i].y - mean)*rstd*sc.y + of.y);
      pk.z = (short)f2bf((v[i].z - mean)*rstd*sc.z + of.z);
      pk.w = (short)f2bf((v[i].w - mean)*rstd*sc.w + of.w);
      *(s16x4*)&xs[r][q*32 + i*4] = pk;
    }
    if (t < 64) msk[t] = mask[m0 + t];
  }
  __syncthreads();

  const int w = t >> 6, L = t & 63, ln16 = L & 15, quad = L >> 4;
  // A fragments: A[m=lane&15][k=quad*8+j], rows = x rows
  bf16v8 af[4][4];
  #pragma unroll
  for (int rs = 0; rs < 4; ++rs)
    #pragma unroll
    for (int kk = 0; kk < 4; ++kk)
      af[rs][kk] = *(const bf16v8*)&xs[rs*16 + ln16][kk*32 + quad*8];

  const f32x4 zero4 = {0.f,0.f,0.f,0.f};
  // proj/gate pairs: wave w owns d-cols [64w, 64w+64)
  #pragma unroll
  for (int pp = 0; pp < 4; ++pp){
    const int p = w*4 + pp;
    const u16* wpr = wt + (size_t)(16*p + ln16)*CDIM + quad*8;
    const u16* wgr = wpr + (size_t)256*CDIM;
    bf16v8 bp[4], bg[4];
    #pragma unroll
    for (int kk = 0; kk < 4; ++kk){
      bp[kk] = *(const bf16v8*)(wpr + kk*32);
      bg[kk] = *(const bf16v8*)(wgr + kk*32);
    }
    f32x4 aP[4] = {zero4, zero4, zero4, zero4};
    f32x4 aG[4] = {zero4, zero4, zero4, zero4};
    #pragma unroll
    for (int kk = 0; kk < 4; ++kk)
      #pragma unroll
      for (int rs = 0; rs < 4; ++rs){
        aP[rs] = mfma_bf16(af[rs][kk], bp[kk], aP[rs]);
        aG[rs] = mfma_bf16(af[rs][kk], bg[kk], aG[rs]);
      }
    #pragma unroll
    for (int rs = 0; rs < 4; ++rs)
      #pragma unroll
      for (int reg = 0; reg < 4; ++reg){
        const int ml = rs*16 + quad*4 + reg;          // C/D: row=quad*4+reg
        const float pg = aP[rs][reg] * sigm(aG[rs][reg]) * msk[ml];
        pgs[16*p + ln16][ml] = f2bf(pg);              // C/D: col=lane&15
      }
  }
  // gate_out tiles: wave w owns e-cols [32w, 32w+32)
  #pragma unroll
  for (int u = 0; u < 2; ++u){
    const int e0 = 32*w + 16*u;
    const u16* wr = wt + (size_t)(512 + e0 + ln16)*CDIM + quad*8;
    bf16v8 bb[4];
    #pragma unroll
    for (int kk = 0; kk < 4; ++kk) bb[kk] = *(const bf16v8*)(wr + kk*32);
    f32x4 ag[4] = {zero4, zero4, zero4, zero4};
    #pragma unroll
    for (int kk = 0; kk < 4; ++kk)
      #pragma unroll
      for (int rs = 0; rs < 4; ++rs)
        ag[rs] = mfma_bf16(af[rs][kk], bb[kk], ag[rs]);
    const int e = e0 + ln16;
    const float bias = bgo[e];
    #pragma unroll
    for (int rs = 0; rs < 4; ++rs)
      #pragma unroll
      for (int reg = 0; reg < 4; ++reg){
        const int ml = rs*16 + quad*4 + reg;
        gate[(size_t)(m0 + ml)*CDIM + e] = sigm(ag[rs][reg] + bias);
      }
  }
  __syncthreads();

  // AB store: channel-major, 64 contiguous m per block per channel
  #pragma unroll
  for (int p4 = 0; p4 < 4; ++p4){
    const int d = p4*64 + (t >> 2), q = t & 3;
    u16* dst = AB + (size_t)d*MDIM + m0 + q*16;
    const u16* src = &pgs[d][q*16];
    *(bf16v8*)dst       = *(const bf16v8*)src;
    *(bf16v8*)(dst + 8) = *(const bf16v8*)(src + 8);
  }
}

// ---------------------------------------------------------------------------
// K2: per-channel triangle GEMM act2[c] = a[c] @ b[c]^T  (a=AB[2c], b=AB[2c+1])
//     128x128 tile, BK=64, 4 waves * (64x64, 4x4 accs). gemm_bt structure.
// ---------------------------------------------------------------------------
__global__ __launch_bounds__(256) void k2_tri(const u16* __restrict__ AB,
                                              u16* __restrict__ act2)
{
  __shared__ __align__(16) u16 As[128][72];
  __shared__ __align__(16) u16 Bs[128][72];
  const int t = threadIdx.x, bid = blockIdx.x;
  const int c  = bid >> 4;
  const int i0 = ((bid >> 2) & 3) * 128;
  const int j0 = (bid & 3) * 128;
  const u16* Ag = AB + (size_t)(2*c)*MDIM;
  const u16* Bg = AB + (size_t)(2*c + 1)*MDIM;

  const int w = t >> 6, L = t & 63, ln16 = L & 15, quad = L >> 4;
  const int iw = (w & 1)*64, jw = (w >> 1)*64;
  const int r = t >> 1, h = t & 1;   // staging: row r, 64B half h

  const f32x4 zero4 = {0.f,0.f,0.f,0.f};
  f32x4 acc[4][4];
  #pragma unroll
  for (int x = 0; x < 4; ++x)
    #pragma unroll
    for (int y = 0; y < 4; ++y) acc[x][y] = zero4;

  for (int k0 = 0; k0 < NDIM; k0 += 64){
    const u16* ga = Ag + (size_t)(i0 + r)*NDIM + k0 + h*32;
    const u16* gb = Bg + (size_t)(j0 + r)*NDIM + k0 + h*32;
    bf16v8 sa[4], sb[4];
    #pragma unroll
    for (int x = 0; x < 4; ++x){
      sa[x] = *(const bf16v8*)(ga + x*8);
      sb[x] = *(const bf16v8*)(gb + x*8);
    }
    __syncthreads();                // prior iter's LDS reads complete
    #pragma unroll
    for (int x = 0; x < 4; ++x){
      *(bf16v8*)&As[r][h*32 + x*8] = sa[x];
      *(bf16v8*)&Bs[r][h*32 + x*8] = sb[x];
    }
    __syncthreads();
    #pragma unroll
    for (int kk = 0; kk < 2; ++kk){
      bf16v8 ar[4], br[4];
      #pragma unroll
      for (int x = 0; x < 4; ++x) ar[x] = *(const bf16v8*)&As[iw + x*16 + ln16][kk*32 + quad*8];
      #pragma unroll
      for (int y = 0; y < 4; ++y) br[y] = *(const bf16v8*)&Bs[jw + y*16 + ln16][kk*32 + quad*8];
      #pragma unroll
      for (int x = 0; x < 4; ++x)
        #pragma unroll
        for (int y = 0; y < 4; ++y)
          acc[x][y] = mfma_bf16(ar[x], br[y], acc[x][y]);
    }
  }

  u16* op = act2 + (size_t)c*MDIM;
  #pragma unroll
  for (int x = 0; x < 4; ++x)
    #pragma unroll
    for (int y = 0; y < 4; ++y)
      #pragma unroll
      for (int reg = 0; reg < 4; ++reg){
        const int il = iw + x*16 + quad*4 + reg;
        const int jl = jw + y*16 + ln16;
        op[(size_t)(i0 + il)*NDIM + j0 + jl] = f2bf(acc[x][y][reg]);
      }
}

// ---------------------------------------------------------------------------
// K3: per (i, 64 j's): gather act2[:,i,j] (transposed tile), channel-LN over c,
//     MFMA with w_out^T + b_out, multiply by gate (in d_out), store fp32.
// ---------------------------------------------------------------------------
__global__ __launch_bounds__(256) void k3_out(
    const u16* __restrict__ act2, const u16* __restrict__ wt2,
    const float* __restrict__ cns, const float* __restrict__ cno,
    const float* __restrict__ bo, float* __restrict__ out)
{
  __shared__ __align__(16) float vs[128][65];    // [c][jj]
  __shared__ __align__(16) u16 xs2[64][136];     // [jj][c] normalized bf16
  __shared__ float csh[128], coh[128];
  const int t = threadIdx.x;
  const int i  = blockIdx.x >> 3;
  const int j0 = (blockIdx.x & 7)*64;
  if (t < 128){ csh[t] = cns[t]; coh[t] = cno[t]; }

  { // load transposed tile
    const int cc = t >> 1, h = t & 1;
    const u16* g = act2 + (size_t)cc*MDIM + (size_t)i*NDIM + j0 + h*32;
    #pragma unroll
    for (int x = 0; x < 4; ++x){
      bf16v8 uv = *(const bf16v8*)(g + x*8);
      #pragma unroll
      for (int e = 0; e < 8; ++e) vs[cc][h*32 + x*8 + e] = (float)uv[e];
    }
  }
  __syncthreads();
  { // stats over c per jj (4 threads/jj, c interleaved by q to dodge banks)
    const int jj = t >> 2, q = t & 3;
    float s = 0.f, s2 = 0.f;
    #pragma unroll
    for (int ci = 0; ci < 32; ++ci){
      const float v = vs[4*ci + q][jj];
      s += v; s2 += v*v;
    }
    s += __shfl_xor(s,1); s2 += __shfl_xor(s2,1);
    s += __shfl_xor(s,2); s2 += __shfl_xor(s2,2);
    const float mean = s*(1.f/128.f);
    const float rstd = rsqrtf(s2*(1.f/128.f) - mean*mean + 1e-5f);
    #pragma unroll
    for (int ci = 0; ci < 32; ++ci){
      const int cc = 4*ci + q;
      xs2[jj][cc] = f2bf((vs[cc][jj] - mean)*rstd*csh[cc] + coh[cc]);
    }
  }
  __syncthreads();

  const int w = t >> 6, L = t & 63, ln16 = L & 15, quad = L >> 4;
  bf16v8 af[4];
  #pragma unroll
  for (int kk = 0; kk < 4; ++kk)
    af[kk] = *(const bf16v8*)&xs2[w*16 + ln16][kk*32 + quad*8];
  const f32x4 zero4 = {0.f,0.f,0.f,0.f};
  #pragma unroll
  for (int n = 0; n < 8; ++n){
    const u16* wr = wt2 + (size_t)(n*16 + ln16)*CDIM + quad*8;
    bf16v8 bb[4];
    #pragma unroll
    for (int kk = 0; kk < 4; ++kk) bb[kk] = *(const bf16v8*)(wr + kk*32);
    f32x4 ac = zero4;
    #pragma unroll
    for (int kk = 0; kk < 4; ++kk) ac = mfma_bf16(af[kk], bb[kk], ac);
    const int e = n*16 + ln16;
    const float bias = bo[e];
    #pragma unroll
    for (int reg = 0; reg < 4; ++reg){
      const int jl = w*16 + quad*4 + reg;
      const size_t idx = ((size_t)i*NDIM + j0 + jl)*(size_t)CDIM + e;
      out[idx] = (ac[reg] + bias) * out[idx];   // gate was staged here by K1
    }
  }
}

// ---------------------------------------------------------------------------
extern "C" void kernel_launch(void* const* d_in, const int* in_sizes, int n_in,
                              void* d_out, int out_size, void* d_ws, size_t ws_size,
                              hipStream_t stream)
{
  const float* act = (const float*)d_in[0];
  const float* msk = (const float*)d_in[1];
  const float* lns = (const float*)d_in[2];
  const float* lno = (const float*)d_in[3];
  const float* wp  = (const float*)d_in[4];
  const float* wg  = (const float*)d_in[5];
  const float* cns = (const float*)d_in[6];
  const float* cno = (const float*)d_in[7];
  const float* wo  = (const float*)d_in[8];
  const float* bo  = (const float*)d_in[9];
  const float* wgo = (const float*)d_in[10];
  const float* bgo = (const float*)d_in[11];
  float* out = (float*)d_out;

  // ws layout: AB (256*M bf16, 128 MiB) | ACT2 (128*M bf16, 64 MiB) | WT (768*128 bf16)
  u16* AB   = (u16*)d_ws;
  u16* ACT2 = AB + (size_t)256*MDIM;
  u16* WT   = ACT2 + (size_t)128*MDIM;

  k0_prep   <<<dim3(768),  dim3(128), 0, stream>>>(wp, wg, wgo, wo, WT);
  k1_ln_proj<<<dim3(4096), dim3(256), 0, stream>>>(act, msk, lns, lno, bgo, WT, AB, out);
  k2_tri    <<<dim3(2048), dim3(256), 0, stream>>>(AB, ACT2);
  k3_out    <<<dim3(4096), dim3(256), 0, stream>>>(ACT2, WT + 640*CDIM, cns, cno, bo, out);
}